// Round 1
// baseline (299.602 us; speedup 1.0000x reference)
//
#include <hip/hip_runtime.h>
#include <cstdint>

#define DEV __device__ __forceinline__

typedef float f32x4 __attribute__((ext_vector_type(4)));
typedef short s16x8 __attribute__((ext_vector_type(8)));

DEV unsigned short f2bf(float f){
    unsigned u = __builtin_bit_cast(unsigned, f);
    u = u + 0x7fffu + ((u >> 16) & 1u);   // RNE
    return (unsigned short)(u >> 16);
}
DEV float bf2f(unsigned short h){
    unsigned u = ((unsigned)h) << 16;
    return __builtin_bit_cast(float, u);
}

typedef const void __attribute__((address_space(1)))* gcp;
typedef void __attribute__((address_space(3)))* lp;
DEV void gload_lds16(const void* g, void* l){
    // async global->LDS, 16B per lane; LDS dest = wave-uniform base + lane*16
    __builtin_amdgcn_global_load_lds((gcp)g, (lp)l, 16, 0, 0);
}

// ---------------------------------------------------------------------------
// Prep: dragon pattern (deterministic), blend scalar, zero Vmean.
// pattern[11] has length 4095 = 2*2048-1, np.interp to 2048 picks element 2i.
// ---------------------------------------------------------------------------
__global__ __launch_bounds__(256) void k_prep(
    const float* __restrict__ scale, const float* __restrict__ bias,
    const float* __restrict__ w1, const float* __restrict__ b1,
    const float* __restrict__ w2, const float* __restrict__ b2,
    float* __restrict__ dragon_w, float* __restrict__ blend_out,
    float* __restrict__ vmean)
{
    __shared__ float A[4095];
    __shared__ float Bb[4095];
    __shared__ float sred[256];
    __shared__ float smn, smx;
    int tid = threadIdx.x;

    for (int i = tid; i < 4096; i += 256) vmean[i] = 0.f;   // 8*512

    if (tid == 0) A[0] = 0.5f;
    __syncthreads();
    int len = 1;
    for (int it = 1; it < 12; ++it){
        int n = len, nl = 2*n + 1;
        // expand: [prev, 0.5, 1 - reverse(prev)]
        for (int i = tid; i < nl; i += 256){
            float v;
            if (i < n)       v = A[i];
            else if (i == n) v = 0.5f;
            else             v = 1.0f - A[2*n - i];
            Bb[i] = v;
        }
        __syncthreads();
        // conv1d kernel=[1/3,1/3,1/3], zero pad, 'same'
        const float third = 1.0f/3.0f;
        for (int i = tid; i < nl; i += 256){
            float s = Bb[i]*third;
            if (i > 0)    s += Bb[i-1]*third;
            if (i < nl-1) s += Bb[i+1]*third;
            A[i] = s;
        }
        __syncthreads();
        // min/max
        float mn = 3.4e38f, mx = -3.4e38f;
        for (int i = tid; i < nl; i += 256){ float v = A[i]; mn = fminf(mn,v); mx = fmaxf(mx,v); }
        sred[tid] = mn; __syncthreads();
        for (int off = 128; off > 0; off >>= 1){
            if (tid < off) sred[tid] = fminf(sred[tid], sred[tid+off]);
            __syncthreads();
        }
        if (tid == 0) smn = sred[0];
        __syncthreads();
        sred[tid] = mx; __syncthreads();
        for (int off = 128; off > 0; off >>= 1){
            if (tid < off) sred[tid] = fmaxf(sred[tid], sred[tid+off]);
            __syncthreads();
        }
        if (tid == 0) smx = sred[0];
        __syncthreads();
        float lo = smn, den = smx - lo + 1e-8f;
        for (int i = tid; i < nl; i += 256) A[i] = (A[i] - lo) / den;
        len = nl;
        __syncthreads();
    }
    // dragon_w[s] = softplus(pattern[2s]*scale[11] + bias[11])
    float sc = scale[11], bi = bias[11];
    for (int i = tid; i < 2048; i += 256){
        float x = A[2*i]*sc + bi;
        dragon_w[i] = fmaxf(x, 0.f) + log1pf(__expf(-fabsf(x)));
    }
    // blend = sigmoid(relu(w1[11,:]+b1) @ w2 + b2)
    if (tid < 64){
        float h = fmaxf(w1[11*64 + tid] + b1[tid], 0.f);
        float c = h * w2[tid];
        for (int off = 32; off > 0; off >>= 1) c += __shfl_xor(c, off, 64);
        if (tid == 0){
            float z = c + b2[0];
            blend_out[0] = 1.f/(1.f + __expf(-z));
        }
    }
}

// ---------------------------------------------------------------------------
// Convert Q -> bf16, K*w[s] -> bf16
// ---------------------------------------------------------------------------
__global__ __launch_bounds__(256) void k_convqk(
    const float* __restrict__ Q, const float* __restrict__ K,
    const float* __restrict__ dragon_w,
    unsigned short* __restrict__ Qb, unsigned short* __restrict__ Kb)
{
    const long long total4 = (long long)8*2048*512/4;
    long long stride = (long long)gridDim.x * blockDim.x;
    for (long long i = (long long)blockIdx.x*blockDim.x + threadIdx.x; i < total4; i += stride){
        long long base = i*4;
        int s = (int)((base >> 9) & 2047);
        float w = dragon_w[s];
        const float4 q = *(const float4*)(Q + base);
        const float4 k = *(const float4*)(K + base);
        ushort4 qo, ko;
        qo.x = f2bf(q.x);   qo.y = f2bf(q.y);   qo.z = f2bf(q.z);   qo.w = f2bf(q.w);
        ko.x = f2bf(k.x*w); ko.y = f2bf(k.y*w); ko.z = f2bf(k.z*w); ko.w = f2bf(k.w*w);
        *(ushort4*)(Qb + base) = qo;
        *(ushort4*)(Kb + base) = ko;
    }
}

// ---------------------------------------------------------------------------
// V -> Vt (bf16, transposed [b][d][s]) + Vmean[b][d] = mean_s V
// ---------------------------------------------------------------------------
__global__ __launch_bounds__(256) void k_convv(
    const float* __restrict__ V, unsigned short* __restrict__ Vt,
    float* __restrict__ vmean)
{
    __shared__ float tile[64][66];   // pad 2 -> conflict-free transposed reads
    int tid = threadIdx.x;
    int tx = tid & 63, ty = tid >> 6;
    int s0 = blockIdx.x*64, d0 = blockIdx.y*64, b = blockIdx.z;
    const float* src = V + ((long long)b*2048 + s0)*512 + d0;
    #pragma unroll
    for (int r = 0; r < 16; ++r){
        int row = r*4 + ty;
        tile[row][tx] = src[(long long)row*512 + tx];
    }
    __syncthreads();
    unsigned short* dst = Vt + ((long long)b*512 + d0)*2048 + s0;
    #pragma unroll
    for (int r = 0; r < 16; ++r){
        int drow = r*4 + ty;
        dst[(long long)drow*2048 + tx] = f2bf(tile[tx][drow]);
    }
    // Vmean partials
    int dcol = tid & 63, sp = tid >> 6;
    float s = 0.f;
    #pragma unroll
    for (int ii = 0; ii < 16; ++ii) s += tile[sp*16 + ii][dcol];
    atomicAdd(&vmean[b*512 + d0 + dcol], s * (1.0f/2048.0f));
}

// ---------------------------------------------------------------------------
// GEMM 1: Sp[b,q,k] = bf16( exp( (Qb . Kb^T) / sqrt(512) ) )
// 128x128 tile, BK=64, 4 waves (2x2), 4x4 MFMA 16x16x32 per wave.
// ---------------------------------------------------------------------------
#define SCALE_QK 0.04419417382415922f

__global__ __launch_bounds__(256) void k_gemm_qk(
    const unsigned short* __restrict__ Qb, const unsigned short* __restrict__ Kb,
    unsigned short* __restrict__ Sp)
{
    __shared__ unsigned short At[128*64];
    __shared__ unsigned short Bt[128*64];
    int tid = threadIdx.x;
    int lane = tid & 63, wave = tid >> 6;
    int wm = wave >> 1, wn = wave & 1;
    int ln = lane & 15, q4 = lane >> 4;
    int q0 = blockIdx.y*128, k0 = blockIdx.x*128, b = blockIdx.z;
    const unsigned short* Abase = Qb + ((long long)b*2048 + q0)*512;
    const unsigned short* Bbase = Kb + ((long long)b*2048 + k0)*512;

    f32x4 acc[4][4];
    #pragma unroll
    for (int i = 0; i < 4; ++i)
        #pragma unroll
        for (int j = 0; j < 4; ++j) acc[i][j] = (f32x4)0.0f;

    for (int kt = 0; kt < 8; ++kt){
        #pragma unroll
        for (int c = 0; c < 4; ++c){
            int chunk = wave*4 + c;                // 16 x 1KB chunks per tile
            int row = chunk*8 + (lane >> 3);
            int col = (lane & 7)*8;
            gload_lds16(Abase + (long long)row*512 + kt*64 + col, &At[chunk*512]);
            gload_lds16(Bbase + (long long)row*512 + kt*64 + col, &Bt[chunk*512]);
        }
        __syncthreads();
        #pragma unroll
        for (int ks = 0; ks < 2; ++ks){
            s16x8 af[4], bfr[4];
            #pragma unroll
            for (int i = 0; i < 4; ++i)
                af[i] = *(const s16x8*)&At[(wm*64 + i*16 + ln)*64 + ks*32 + q4*8];
            #pragma unroll
            for (int j = 0; j < 4; ++j)
                bfr[j] = *(const s16x8*)&Bt[(wn*64 + j*16 + ln)*64 + ks*32 + q4*8];
            #pragma unroll
            for (int i = 0; i < 4; ++i)
                #pragma unroll
                for (int j = 0; j < 4; ++j)
                    acc[i][j] = __builtin_amdgcn_mfma_f32_16x16x32_bf16(af[i], bfr[j], acc[i][j], 0, 0, 0);
        }
        __syncthreads();
    }
    unsigned short* outp = Sp + (long long)b*2048*2048;
    #pragma unroll
    for (int i = 0; i < 4; ++i){
        #pragma unroll
        for (int j = 0; j < 4; ++j){
            #pragma unroll
            for (int r = 0; r < 4; ++r){
                int q = q0 + wm*64 + i*16 + q4*4 + r;   // C/D: row=(lane>>4)*4+reg
                int k = k0 + wn*64 + j*16 + ln;         //      col=lane&15
                float v = __expf(acc[i][j][r] * SCALE_QK);
                outp[(long long)q*2048 + k] = f2bf(v);
            }
        }
    }
}

// ---------------------------------------------------------------------------
// GEMM 2: out[b,q,d] = blend * (Sp . V) / l[q] + (1-blend) * Vmean[d]
// l[q] = sum_k Sp[q,k] accumulated from the A-fragments (wn==0 waves only).
// ---------------------------------------------------------------------------
__global__ __launch_bounds__(256) void k_gemm_pv(
    const unsigned short* __restrict__ Sp, const unsigned short* __restrict__ Vt,
    const float* __restrict__ vmean, const float* __restrict__ blendp,
    float* __restrict__ out)
{
    __shared__ unsigned short At[128*64];
    __shared__ unsigned short Bt[128*64];
    __shared__ float l_sh[128];
    int tid = threadIdx.x;
    int lane = tid & 63, wave = tid >> 6;
    int wm = wave >> 1, wn = wave & 1;
    int ln = lane & 15, q4 = lane >> 4;
    int q0 = blockIdx.y*128, d0 = blockIdx.x*128, b = blockIdx.z;
    const unsigned short* Abase = Sp + (long long)b*2048*2048 + (long long)q0*2048;
    const unsigned short* Bbase = Vt + ((long long)b*512 + d0)*2048;

    f32x4 acc[4][4];
    #pragma unroll
    for (int i = 0; i < 4; ++i)
        #pragma unroll
        for (int j = 0; j < 4; ++j) acc[i][j] = (f32x4)0.0f;
    float lsum[4] = {0.f, 0.f, 0.f, 0.f};

    for (int kt = 0; kt < 32; ++kt){
        #pragma unroll
        for (int c = 0; c < 4; ++c){
            int chunk = wave*4 + c;
            int row = chunk*8 + (lane >> 3);
            int col = (lane & 7)*8;
            gload_lds16(Abase + (long long)row*2048 + kt*64 + col, &At[chunk*512]);
            gload_lds16(Bbase + (long long)row*2048 + kt*64 + col, &Bt[chunk*512]);
        }
        __syncthreads();
        #pragma unroll
        for (int ks = 0; ks < 2; ++ks){
            s16x8 af[4], bfr[4];
            #pragma unroll
            for (int i = 0; i < 4; ++i)
                af[i] = *(const s16x8*)&At[(wm*64 + i*16 + ln)*64 + ks*32 + q4*8];
            #pragma unroll
            for (int j = 0; j < 4; ++j)
                bfr[j] = *(const s16x8*)&Bt[(wn*64 + j*16 + ln)*64 + ks*32 + q4*8];
            if (wn == 0){
                // A-frag: lane holds P[m=ln][k..k+7] -> row sums for l
                #pragma unroll
                for (int i = 0; i < 4; ++i){
                    float s = 0.f;
                    #pragma unroll
                    for (int jj = 0; jj < 8; ++jj) s += bf2f((unsigned short)af[i][jj]);
                    lsum[i] += s;
                }
            }
            #pragma unroll
            for (int i = 0; i < 4; ++i)
                #pragma unroll
                for (int j = 0; j < 4; ++j)
                    acc[i][j] = __builtin_amdgcn_mfma_f32_16x16x32_bf16(af[i], bfr[j], acc[i][j], 0, 0, 0);
        }
        __syncthreads();
    }
    if (wn == 0){
        #pragma unroll
        for (int i = 0; i < 4; ++i){
            float v = lsum[i];
            v += __shfl_xor(v, 16, 64);
            v += __shfl_xor(v, 32, 64);
            if (lane < 16) l_sh[wm*64 + i*16 + lane] = v;
        }
    }
    __syncthreads();

    float blend = blendp[0];
    float ib = 1.0f - blend;
    float* obase = out + ((long long)b*2048 + q0)*512 + d0;
    float vm[4];
    #pragma unroll
    for (int j = 0; j < 4; ++j) vm[j] = vmean[b*512 + d0 + wn*64 + j*16 + ln];
    #pragma unroll
    for (int i = 0; i < 4; ++i){
        #pragma unroll
        for (int r = 0; r < 4; ++r){
            int ql = wm*64 + i*16 + q4*4 + r;
            float linv = 1.0f / l_sh[ql];
            #pragma unroll
            for (int j = 0; j < 4; ++j){
                int dl = wn*64 + j*16 + ln;
                obase[(long long)ql*512 + dl] = blend*acc[i][j][r]*linv + ib*vm[j];
            }
        }
    }
}

// ---------------------------------------------------------------------------
extern "C" void kernel_launch(void* const* d_in, const int* in_sizes, int n_in,
                              void* d_out, int out_size, void* d_ws, size_t ws_size,
                              hipStream_t stream)
{
    (void)in_sizes; (void)n_in; (void)out_size; (void)ws_size;
    const float* Q  = (const float*)d_in[0];
    const float* K  = (const float*)d_in[1];
    const float* V  = (const float*)d_in[2];
    const float* ps = (const float*)d_in[3];
    const float* pb = (const float*)d_in[4];
    const float* w1 = (const float*)d_in[5];
    const float* b1 = (const float*)d_in[6];
    const float* w2 = (const float*)d_in[7];
    const float* b2 = (const float*)d_in[8];
    float* out = (float*)d_out;

    char* ws = (char*)d_ws;
    float* dragon_w        = (float*)(ws);                                        // 8 KiB
    float* blend           = (float*)(ws + 8192);
    float* vmean           = (float*)(ws + 16384);                                // 16 KiB
    unsigned short* Qb     = (unsigned short*)(ws + 32768);                       // 16 MiB
    unsigned short* Kb     = (unsigned short*)(ws + 32768 + (size_t)16*1024*1024);// 16 MiB
    unsigned short* Vt     = (unsigned short*)(ws + 32768 + (size_t)32*1024*1024);// 16 MiB
    unsigned short* Sp     = (unsigned short*)(ws + 32768 + (size_t)48*1024*1024);// 64 MiB

    hipLaunchKernelGGL(k_prep,    dim3(1),         dim3(256), 0, stream,
                       ps, pb, w1, b1, w2, b2, dragon_w, blend, vmean);
    hipLaunchKernelGGL(k_convqk,  dim3(2048),      dim3(256), 0, stream,
                       Q, K, dragon_w, Qb, Kb);
    hipLaunchKernelGGL(k_convv,   dim3(32, 8, 8),  dim3(256), 0, stream,
                       V, Vt, vmean);
    hipLaunchKernelGGL(k_gemm_qk, dim3(16, 16, 8), dim3(256), 0, stream,
                       Qb, Kb, Sp);
    hipLaunchKernelGGL(k_gemm_pv, dim3(4, 16, 8),  dim3(256), 0, stream,
                       Sp, Vt, vmean, blend, out);
}

// Round 2
// 254.463 us; speedup vs baseline: 1.1774x; 1.1774x over previous
//
#include <hip/hip_runtime.h>
#include <cstdint>

#define DEV __device__ __forceinline__

typedef float f32x4 __attribute__((ext_vector_type(4)));
typedef short s16x8 __attribute__((ext_vector_type(8)));

DEV unsigned short f2bf(float f){
    unsigned u = __builtin_bit_cast(unsigned, f);
    u = u + 0x7fffu + ((u >> 16) & 1u);   // RNE
    return (unsigned short)(u >> 16);
}
DEV float bf2f(unsigned short h){
    unsigned u = ((unsigned)h) << 16;
    return __builtin_bit_cast(float, u);
}

typedef const void __attribute__((address_space(1)))* gcp;
typedef void __attribute__((address_space(3)))* lp;
DEV void gload_lds16(const void* g, void* l){
    // async global->LDS, 16B per lane; LDS dest = wave-uniform base + lane*16
    __builtin_amdgcn_global_load_lds((gcp)g, (lp)l, 16, 0, 0);
}

// ---------------------------------------------------------------------------
// Stage 1 (grid 4097):
//   block 0        : dragon pattern + blend scalar (single block, hidden
//                    behind the conversion blocks running concurrently)
//   blocks 1..2048 : Q -> bf16
//   blocks 2049..  : V -> Vt (bf16 [b][d][s]) + race-free vmean partials
// ---------------------------------------------------------------------------
__global__ __launch_bounds__(256) void k_stage1(
    const float* __restrict__ Q, const float* __restrict__ V,
    const float* __restrict__ scale, const float* __restrict__ bias,
    const float* __restrict__ w1, const float* __restrict__ b1,
    const float* __restrict__ w2, const float* __restrict__ b2,
    float* __restrict__ dragon_w, float* __restrict__ blend_out,
    unsigned short* __restrict__ Qb, unsigned short* __restrict__ Vt,
    float* __restrict__ vmean_part)
{
    __shared__ float sh[8704];
    int tid = threadIdx.x;
    int bx  = blockIdx.x;

    if (bx == 0){
        // ---- dragon pattern prep ----
        float* A    = sh;          // 4096
        float* Bb   = sh + 4096;   // 4096
        float* sred = sh + 8192;   // 512 (min at [0..255], max at [256..511])
        if (tid == 0) A[0] = 0.5f;
        __syncthreads();
        int len = 1;
        for (int it = 1; it < 12; ++it){
            int n = len, nl = 2*n + 1;
            for (int i = tid; i < nl; i += 256){
                float v;
                if (i < n)       v = A[i];
                else if (i == n) v = 0.5f;
                else             v = 1.0f - A[2*n - i];
                Bb[i] = v;
            }
            __syncthreads();
            const float third = 1.0f/3.0f;
            for (int i = tid; i < nl; i += 256){
                float s = Bb[i]*third;
                if (i > 0)    s += Bb[i-1]*third;
                if (i < nl-1) s += Bb[i+1]*third;
                A[i] = s;
            }
            __syncthreads();
            float mn = 3.4e38f, mx = -3.4e38f;
            for (int i = tid; i < nl; i += 256){ float v = A[i]; mn = fminf(mn,v); mx = fmaxf(mx,v); }
            sred[tid] = mn; sred[256 + tid] = mx;
            __syncthreads();
            for (int off = 128; off > 0; off >>= 1){
                if (tid < off){
                    sred[tid]       = fminf(sred[tid],       sred[tid+off]);
                    sred[256 + tid] = fmaxf(sred[256 + tid], sred[256 + tid + off]);
                }
                __syncthreads();
            }
            float lo = sred[0], den = sred[256] - lo + 1e-8f;
            for (int i = tid; i < nl; i += 256) A[i] = (A[i] - lo) / den;
            len = nl;
            __syncthreads();
        }
        // pattern[11] has length 4095 = 2*2048-1 -> np.interp picks element 2i
        float sc = scale[11], bi = bias[11];
        for (int i = tid; i < 2048; i += 256){
            float x = A[2*i]*sc + bi;
            dragon_w[i] = fmaxf(x, 0.f) + log1pf(__expf(-fabsf(x)));  // softplus
        }
        // blend = sigmoid(relu(w1[11,:]+b1) @ w2 + b2)
        if (tid < 64){
            float h = fmaxf(w1[11*64 + tid] + b1[tid], 0.f);
            float c = h * w2[tid];
            for (int off = 32; off > 0; off >>= 1) c += __shfl_xor(c, off, 64);
            if (tid == 0) blend_out[0] = 1.f/(1.f + __expf(-(c + b2[0])));
        }
        return;
    }

    if (bx <= 2048){
        // ---- Q -> bf16 ----
        const long long total4 = (long long)8*2048*512/4;   // 2097152
        long long stride = 2048LL*256;
        for (long long i = (long long)(bx-1)*256 + tid; i < total4; i += stride){
            long long base = i*4;
            const float4 q = *(const float4*)(Q + base);
            ushort4 qo;
            qo.x = f2bf(q.x); qo.y = f2bf(q.y); qo.z = f2bf(q.z); qo.w = f2bf(q.w);
            *(ushort4*)(Qb + base) = qo;
        }
        return;
    }

    // ---- V transpose + vmean partials ----
    int t = bx - 2049;                    // 0..2047 = 32 stile x 8 dtile x 8 b
    int stile = t & 31, dtile = (t >> 5) & 7, b = t >> 8;
    int s0 = stile*64, d0 = dtile*64;
    float (*tile)[66] = (float(*)[66])sh;  // 64x66 = 4224 floats
    float* red = sh + 4352;                // 256 floats
    int tx = tid & 63, ty = tid >> 6;
    const float* src = V + ((long long)b*2048 + s0)*512 + d0;
    #pragma unroll
    for (int r = 0; r < 16; ++r){
        int row = r*4 + ty;
        tile[row][tx] = src[(long long)row*512 + tx];
    }
    __syncthreads();
    unsigned short* dst = Vt + ((long long)b*512 + d0)*2048 + s0;
    #pragma unroll
    for (int r = 0; r < 16; ++r){
        int drow = r*4 + ty;
        dst[(long long)drow*2048 + tx] = f2bf(tile[tx][drow]);
    }
    // vmean partial: sum over the 64 s-rows of this tile (race-free per stile)
    int dcol = tid & 63, sp = tid >> 6;
    float s = 0.f;
    #pragma unroll
    for (int ii = 0; ii < 16; ++ii) s += tile[sp*16 + ii][dcol];
    red[sp*64 + dcol] = s;
    __syncthreads();
    if (sp == 0){
        float tot = red[dcol] + red[64+dcol] + red[128+dcol] + red[192+dcol];
        vmean_part[stile*4096 + b*512 + d0 + dcol] = tot * (1.0f/2048.0f);
    }
}

// ---------------------------------------------------------------------------
// Stage 2 (grid 2064): blocks 0..15 reduce vmean partials; rest: K*w -> bf16
// ---------------------------------------------------------------------------
__global__ __launch_bounds__(256) void k_stage2(
    const float* __restrict__ K, const float* __restrict__ dragon_w,
    const float* __restrict__ vmean_part,
    unsigned short* __restrict__ Kb, float* __restrict__ vmean)
{
    int bx = blockIdx.x, tid = threadIdx.x;
    if (bx < 16){
        int idx = bx*256 + tid;            // 0..4095 = b*512+d
        float s = 0.f;
        #pragma unroll
        for (int st = 0; st < 32; ++st) s += vmean_part[st*4096 + idx];
        vmean[idx] = s;
        return;
    }
    const long long total4 = (long long)8*2048*512/4;
    long long stride = 2048LL*256;
    for (long long i = (long long)(bx-16)*256 + tid; i < total4; i += stride){
        long long base = i*4;
        int s = (int)((base >> 9) & 2047);
        float w = dragon_w[s];
        const float4 k = *(const float4*)(K + base);
        ushort4 ko;
        ko.x = f2bf(k.x*w); ko.y = f2bf(k.y*w); ko.z = f2bf(k.z*w); ko.w = f2bf(k.w*w);
        *(ushort4*)(Kb + base) = ko;
    }
}

// ---------------------------------------------------------------------------
// GEMM 1: Sp[b,q,k] = bf16( exp( (Qb . Kb^T) / sqrt(512) ) )
// 128x128 tile, BK=64, 4 waves (2x2), 4x4 MFMA 16x16x32 per wave.
// LDS layout XOR-swizzled: row r's 16B chunk c holds global chunk c^(r&7).
// Kills the 16-way bank conflict on 128B-stride fragment reads while keeping
// global_load_lds's lane-contiguous dest (only free 2-way aliasing remains).
// ---------------------------------------------------------------------------
#define SCALE_QK 0.04419417382415922f

__global__ __launch_bounds__(256) void k_gemm_qk(
    const unsigned short* __restrict__ Qb, const unsigned short* __restrict__ Kb,
    unsigned short* __restrict__ Sp)
{
    __shared__ unsigned short At[128*64];
    __shared__ unsigned short Bt[128*64];
    int tid = threadIdx.x;
    int lane = tid & 63, wave = tid >> 6;
    int wm = wave >> 1, wn = wave & 1;
    int ln = lane & 15, q4 = lane >> 4;
    int sx = ln & 7;                      // fragment-row swizzle key
    int q0 = blockIdx.y*128, k0 = blockIdx.x*128, b = blockIdx.z;
    const unsigned short* Abase = Qb + ((long long)b*2048 + q0)*512;
    const unsigned short* Bbase = Kb + ((long long)b*2048 + k0)*512;

    f32x4 acc[4][4];
    #pragma unroll
    for (int i = 0; i < 4; ++i)
        #pragma unroll
        for (int j = 0; j < 4; ++j) acc[i][j] = (f32x4)0.0f;

    int cc = lane & 7;                    // staging chunk col (LDS side)
    int rg = lane >> 3;                   // staging row within 8-row group
    for (int kt = 0; kt < 8; ++kt){
        #pragma unroll
        for (int c = 0; c < 4; ++c){
            int chunk = wave*4 + c;                 // 16 x 1KB chunks per tile
            int row = chunk*8 + rg;
            int gc  = cc ^ (row & 7);               // swizzled source chunk
            gload_lds16(Abase + (long long)row*512 + kt*64 + gc*8, &At[chunk*512]);
            gload_lds16(Bbase + (long long)row*512 + kt*64 + gc*8, &Bt[chunk*512]);
        }
        __syncthreads();
        #pragma unroll
        for (int ks = 0; ks < 2; ++ks){
            s16x8 af[4], bfr[4];
            int cs = ((ks*4 + q4) ^ sx) * 8;        // swizzled fragment chunk
            #pragma unroll
            for (int i = 0; i < 4; ++i)
                af[i] = *(const s16x8*)&At[(wm*64 + i*16 + ln)*64 + cs];
            #pragma unroll
            for (int j = 0; j < 4; ++j)
                bfr[j] = *(const s16x8*)&Bt[(wn*64 + j*16 + ln)*64 + cs];
            #pragma unroll
            for (int i = 0; i < 4; ++i)
                #pragma unroll
                for (int j = 0; j < 4; ++j)
                    acc[i][j] = __builtin_amdgcn_mfma_f32_16x16x32_bf16(af[i], bfr[j], acc[i][j], 0, 0, 0);
        }
        __syncthreads();
    }
    unsigned short* outp = Sp + (long long)b*2048*2048;
    #pragma unroll
    for (int i = 0; i < 4; ++i){
        #pragma unroll
        for (int j = 0; j < 4; ++j){
            #pragma unroll
            for (int r = 0; r < 4; ++r){
                int q = q0 + wm*64 + i*16 + q4*4 + r;   // C/D: row=(lane>>4)*4+reg
                int k = k0 + wn*64 + j*16 + ln;         //      col=lane&15
                float v = __expf(acc[i][j][r] * SCALE_QK);
                outp[(long long)q*2048 + k] = f2bf(v);
            }
        }
    }
}

// ---------------------------------------------------------------------------
// GEMM 2: out[b,q,d] = blend * (Sp . V) / l[q] + (1-blend) * Vmean[d]
// l[q] = sum_k Sp[q,k] accumulated from the A-fragments (wn==0 waves only).
// Same XOR-swizzled LDS as gemm_qk.
// ---------------------------------------------------------------------------
__global__ __launch_bounds__(256) void k_gemm_pv(
    const unsigned short* __restrict__ Sp, const unsigned short* __restrict__ Vt,
    const float* __restrict__ vmean, const float* __restrict__ blendp,
    float* __restrict__ out)
{
    __shared__ unsigned short At[128*64];
    __shared__ unsigned short Bt[128*64];
    __shared__ float l_sh[128];
    int tid = threadIdx.x;
    int lane = tid & 63, wave = tid >> 6;
    int wm = wave >> 1, wn = wave & 1;
    int ln = lane & 15, q4 = lane >> 4;
    int sx = ln & 7;
    int q0 = blockIdx.y*128, d0 = blockIdx.x*128, b = blockIdx.z;
    const unsigned short* Abase = Sp + (long long)b*2048*2048 + (long long)q0*2048;
    const unsigned short* Bbase = Vt + ((long long)b*512 + d0)*2048;

    f32x4 acc[4][4];
    #pragma unroll
    for (int i = 0; i < 4; ++i)
        #pragma unroll
        for (int j = 0; j < 4; ++j) acc[i][j] = (f32x4)0.0f;
    float lsum[4] = {0.f, 0.f, 0.f, 0.f};

    int cc = lane & 7;
    int rg = lane >> 3;
    for (int kt = 0; kt < 32; ++kt){
        #pragma unroll
        for (int c = 0; c < 4; ++c){
            int chunk = wave*4 + c;
            int row = chunk*8 + rg;
            int gc  = cc ^ (row & 7);
            gload_lds16(Abase + (long long)row*2048 + kt*64 + gc*8, &At[chunk*512]);
            gload_lds16(Bbase + (long long)row*2048 + kt*64 + gc*8, &Bt[chunk*512]);
        }
        __syncthreads();
        #pragma unroll
        for (int ks = 0; ks < 2; ++ks){
            s16x8 af[4], bfr[4];
            int cs = ((ks*4 + q4) ^ sx) * 8;
            #pragma unroll
            for (int i = 0; i < 4; ++i)
                af[i] = *(const s16x8*)&At[(wm*64 + i*16 + ln)*64 + cs];
            #pragma unroll
            for (int j = 0; j < 4; ++j)
                bfr[j] = *(const s16x8*)&Bt[(wn*64 + j*16 + ln)*64 + cs];
            if (wn == 0){
                // A-frag: lane holds P[m=ln][k..k+7] -> row sums for l
                #pragma unroll
                for (int i = 0; i < 4; ++i){
                    float s = 0.f;
                    #pragma unroll
                    for (int jj = 0; jj < 8; ++jj) s += bf2f((unsigned short)af[i][jj]);
                    lsum[i] += s;
                }
            }
            #pragma unroll
            for (int i = 0; i < 4; ++i)
                #pragma unroll
                for (int j = 0; j < 4; ++j)
                    acc[i][j] = __builtin_amdgcn_mfma_f32_16x16x32_bf16(af[i], bfr[j], acc[i][j], 0, 0, 0);
        }
        __syncthreads();
    }
    if (wn == 0){
        #pragma unroll
        for (int i = 0; i < 4; ++i){
            float v = lsum[i];
            v += __shfl_xor(v, 16, 64);
            v += __shfl_xor(v, 32, 64);
            if (lane < 16) l_sh[wm*64 + i*16 + lane] = v;
        }
    }
    __syncthreads();

    float blend = blendp[0];
    float ib = 1.0f - blend;
    float* obase = out + ((long long)b*2048 + q0)*512 + d0;
    float vm[4];
    #pragma unroll
    for (int j = 0; j < 4; ++j) vm[j] = vmean[b*512 + d0 + wn*64 + j*16 + ln];
    #pragma unroll
    for (int i = 0; i < 4; ++i){
        #pragma unroll
        for (int r = 0; r < 4; ++r){
            int ql = wm*64 + i*16 + q4*4 + r;
            float linv = 1.0f / l_sh[ql];
            #pragma unroll
            for (int j = 0; j < 4; ++j){
                int dl = wn*64 + j*16 + ln;
                obase[(long long)ql*512 + dl] = blend*acc[i][j][r]*linv + ib*vm[j];
            }
        }
    }
}

// ---------------------------------------------------------------------------
extern "C" void kernel_launch(void* const* d_in, const int* in_sizes, int n_in,
                              void* d_out, int out_size, void* d_ws, size_t ws_size,
                              hipStream_t stream)
{
    (void)in_sizes; (void)n_in; (void)out_size; (void)ws_size;
    const float* Q  = (const float*)d_in[0];
    const float* K  = (const float*)d_in[1];
    const float* V  = (const float*)d_in[2];
    const float* ps = (const float*)d_in[3];
    const float* pb = (const float*)d_in[4];
    const float* w1 = (const float*)d_in[5];
    const float* b1 = (const float*)d_in[6];
    const float* w2 = (const float*)d_in[7];
    const float* b2 = (const float*)d_in[8];
    float* out = (float*)d_out;

    char* ws = (char*)d_ws;
    float* dragon_w        = (float*)(ws);                                        // 8 KiB
    float* blend           = (float*)(ws + 8192);
    float* vmean           = (float*)(ws + 16384);                                // 16 KiB
    float* vmean_part      = (float*)(ws + 32768);                                // 512 KiB
    size_t off = 32768 + (size_t)512*1024;
    unsigned short* Qb     = (unsigned short*)(ws + off);                         // 16 MiB
    unsigned short* Kb     = (unsigned short*)(ws + off + (size_t)16*1024*1024);  // 16 MiB
    unsigned short* Vt     = (unsigned short*)(ws + off + (size_t)32*1024*1024);  // 16 MiB
    unsigned short* Sp     = (unsigned short*)(ws + off + (size_t)48*1024*1024);  // 64 MiB

    hipLaunchKernelGGL(k_stage1,  dim3(4097),      dim3(256), 0, stream,
                       Q, V, ps, pb, w1, b1, w2, b2, dragon_w, blend, Qb, Vt, vmean_part);
    hipLaunchKernelGGL(k_stage2,  dim3(2064),      dim3(256), 0, stream,
                       K, dragon_w, vmean_part, Kb, vmean);
    hipLaunchKernelGGL(k_gemm_qk, dim3(16, 16, 8), dim3(256), 0, stream,
                       Qb, Kb, Sp);
    hipLaunchKernelGGL(k_gemm_pv, dim3(4, 16, 8),  dim3(256), 0, stream,
                       Sp, Vt, vmean, blend, out);
}